// Round 5
// baseline (198.742 us; speedup 1.0000x reference)
//
#include <hip/hip_runtime.h>
#include <cmath>

typedef float2 c32;

__device__ __forceinline__ void cmadd(c32& acc, c32 a, float cr, float ci){
    acc.x += a.x*cr - a.y*ci;
    acc.y += a.x*ci + a.y*cr;
}

__host__ __device__ constexpr int M12(int x){ return ((x%12)+12)%12; }
__host__ __device__ constexpr int M6(int x){ return ((x%6)+6)%6; }

#define SQ32 0.86602540378443864676f
#define RT22 0.70710678118654752440f
static constexpr float CW12[12] = {1.f, SQ32, 0.5f, 0.f, -0.5f, -SQ32, -1.f, -SQ32, -0.5f, 0.f, 0.5f, SQ32};
static constexpr float SW12[12] = {0.f, 0.5f, SQ32, 1.f, SQ32, 0.5f, 0.f, -0.5f, -SQ32, -1.f, -SQ32, -0.5f};
static constexpr float CW6[6] = {1.f, 0.5f, -0.5f, -1.f, -0.5f, 0.5f};
static constexpr float SW6[6] = {0.f, SQ32, SQ32, 0.f, -SQ32, -SQ32};
static constexpr float CW8[8] = {1.f, RT22, 0.f, -RT22, -1.f, -RT22, 0.f, RT22};
static constexpr float SW8[8] = {0.f, RT22, 1.f, RT22, 0.f, -RT22, -1.f, -RT22};
static constexpr float CW20_[6] = {1.f, 0.95105651629515357212f, 0.80901699437494742410f,
                                   0.58778525229247312917f, 0.30901699437494742410f, 0.f};
static constexpr float SW20_[6] = {0.f, 0.30901699437494742410f, 0.58778525229247312917f,
                                   0.80901699437494742410f, 0.95105651629515357212f, 1.f};

// ---------------- workspace layout ----------------
// float2 region
#define O_CY1  0                   // [8o][66]
#define O_CY2P 528                 // [16o][22cell][8i][5qt]
#define O_XS   (O_CY2P + 14080)    // [2048n][36]
#define O_XS2P (O_XS + 73728)      // [2048n][8i][30slot]
#define N_C32_TOTAL (O_XS2P + 2048*8*30)

// float region
#define O_S2D  0                   // [6l][20k][11mi]
#define O_D1SG 1320                // [6l][3ib][11pi]
#define O_D2SG 1518                // [3l][3ib][5pi][5qi]
#define O_WINT 1743                // [6]
#define O_D1S  1752                // [66cell][8l][12k] sorted-by-lmin cells
#define O_DG   (O_D1S + 6336)      // [30slot][12k]
#define O_D2P  (O_DG + 360)        // [15(m,pi)][6k][4lpad]
#define O_FEAT (O_D2P + 360)       // [2048n][16o]

#define DPI 3.14159265358979323846

// sorted cell enumeration: cells grouped by L = max(m,|p|), m>=0
__device__ __forceinline__ void cell_decode(int c, int& L, int& m, int& p){
    int base;
    if (c < 1){ L=0; base=0; } else if (c < 6){ L=1; base=1; }
    else if (c < 15){ L=2; base=6; } else if (c < 28){ L=3; base=15; }
    else if (c < 45){ L=4; base=28; } else { L=5; base=45; }
    int r = c - base;
    if (r < 2*L){ m = r>>1; p = (r&1)? L : -L; }
    else { m = L; p = (r - 2*L) - L; }
}

// ---------------- Wigner-d via factorial table ----------------
static constexpr double FCT[13] = {1.,1.,2.,6.,24.,120.,720.,5040.,40320.,
                                   362880.,3628800.,39916800.,479001600.};

__device__ __forceinline__ double dipow(double b, int e){
    double r = 1.0;
    while (e){ if (e & 1) r *= b; b *= b; e >>= 1; }
    return r;
}

__device__ double dev_wig(int l, int mp, int m, double beta){
    int k0 = max(0, m - mp), k1 = min(l + m, l - mp);
    double c = cos(0.5*beta), s = sin(0.5*beta);
    double fnum = sqrt(FCT[l+mp]*FCT[l-mp]*FCT[l+m]*FCT[l-m]);
    double acc = 0.0;
    for (int k = k0; k <= k1; ++k){
        double t = fnum / (FCT[l+m-k]*FCT[k]*FCT[mp-m+k]*FCT[l-mp-k])
                 * dipow(c, 2*l-2*k+m-mp) * dipow(s, mp-m+2*k);
        acc += ((mp-m+k) & 1) ? -t : t;
    }
    return acc;
}

__device__ double dev_qw(int b, double beta){
    double s = 0.0;
    for (int j = 0; j < b; ++j) s += sin((2.0*j+1.0)*beta)/(2.0*j+1.0);
    return (2.0/b)*sin(beta)*s;
}

// ---------------- setup pre: D1SG, D2SG, WINT (everything the main setup reads) ----------------
__global__ __launch_bounds__(256) void k_setup_pre(float* fb){
    int gid = blockIdx.x*256 + threadIdx.x;
    if (gid < 198){    // D1SG [6l][3ib][11pi]
        int pi = gid%11; int t = gid/11; int ib = t%3; int l = t/3;
        float v = 0.f;
        if (pi < 2*l+1){ double beta = (ib+1)*DPI/24.0; v = (float)dev_wig(l, pi-l, 0, beta); }
        fb[O_D1SG+gid] = v; return;
    }
    gid -= 198;
    if (gid < 225){    // D2SG [3l][3ib][5pi][5qi]
        int qi = gid%5; int t = gid/5; int pi = t%5; t /= 5; int ib = t%3; int l = t/3;
        float v = 0.f;
        if (pi < 2*l+1 && qi < 2*l+1){ double beta = (ib+1)*DPI/24.0; v = (float)dev_wig(l, pi-l, qi-l, beta); }
        fb[O_D2SG+gid] = v; return;
    }
    gid -= 225;
    if (gid < 6){ double beta = DPI*(2*gid+1)/12.0; fb[O_WINT+gid] = (float)dev_qw(3, beta); return; }
}

// ---------------- setup main: blocks 0..127 = CY2P per (o,i); blocks 128+ = item pool ----------------
__global__ __launch_bounds__(256) void k_setup_main(c32* cb, float* fb,
                                                    const float* __restrict__ w1,
                                                    const float* __restrict__ w2){
    __shared__ float wsh[144];
    __shared__ c32 W1s[3][8][5];
    __shared__ c32 Rs[3][5][5];
    int bid = blockIdx.x, tid = threadIdx.x;
    if (bid < 128){
        // CY2P for (o,i): separable DFT of w2
        int o = bid >> 3, i = bid & 7;
        for (int c = tid; c < 144; c += 256) wsh[c] = w2[(i*16+o)*144 + c];
        __syncthreads();
        for (int c = tid; c < 120; c += 256){
            int ib = c/40, r = c%40, ia = r/5, qi = r%5;
            int q = qi - 2; int qm = ((q%6)+6)%6;
            float wr = CW6[qm], wi = SW6[qm];
            float er = 1.f, ei = 0.f, sx = 0.f, sy = 0.f;
            const float* wrow = wsh + ib*48 + ia*6;
            #pragma unroll
            for (int ig = 0; ig < 6; ++ig){
                float w = wrow[ig];
                sx += w*er; sy += w*ei;
                float nr = er*wr - ei*wi; ei = er*wi + ei*wr; er = nr;
            }
            W1s[ib][ia][qi] = make_float2(sx, sy);
        }
        __syncthreads();
        for (int c = tid; c < 75; c += 256){
            int ib = c/25, r = c%25, pi = r/5, qi = r%5;
            int p = pi - 2; int pm = ((p%8)+8)%8;
            float wr = CW8[pm], wi = SW8[pm];
            float er = 1.f, ei = 0.f;
            c32 acc = make_float2(0.f,0.f);
            #pragma unroll
            for (int ia = 0; ia < 8; ++ia){
                c32 wv = W1s[ib][ia][qi];
                acc.x += wv.x*er - wv.y*ei;
                acc.y += wv.x*ei + wv.y*er;
                float nr = er*wr - ei*wi; ei = er*wi + ei*wr; er = nr;
            }
            Rs[ib][pi][qi] = acc;
        }
        __syncthreads();
        for (int c = tid; c < 110; c += 256){
            int cell = c/5, qt = c%5;
            int l, p;
            if (cell == 0){ l=0; p=0; }
            else if (cell < 7){ l=1; p=(cell-1)%3 - 1; }
            else { l=2; p=(cell-7)%5 - 2; }
            c32 acc = make_float2(0.f,0.f);
            if (qt < 2*l+1){
                int q = qt - l;
                #pragma unroll
                for (int ib = 0; ib < 3; ++ib){
                    float d = fb[O_D2SG + (l*3+ib)*25 + (p+l)*5 + (q+l)];
                    c32 rv = Rs[ib][p+2][q+2];
                    acc.x += d*rv.x; acc.y += d*rv.y;
                }
            }
            cb[O_CY2P + ((o*22+cell)*8 + i)*5 + qt] = acc;
        }
        return;
    }
    // item pool: S2D 1320, CY1 528, D1S 6336, DG 360, D2P 360 = 8904
    int gid = (bid-128)*256 + tid;
    if (gid < 1320){   // S2D [6l][20k][11mi]
        int mi = gid%11; int t = gid/11; int k = t%20; int l = t/20;
        float v = 0.f;
        if (mi < 2*l+1){
            double beta = DPI*(2*k+1)/40.0;
            v = (float)(dev_wig(l, mi-l, 0, beta) * dev_qw(10, beta));
        }
        fb[O_S2D+gid] = v; return;
    }
    gid -= 1320;
    if (gid < 528){    // CY1 [8o][6l][11pi]
        int pi = gid%11; int t = gid/11; int l = t%6; int o = t/6;
        c32 acc = make_float2(0.f,0.f);
        if (pi < 2*l+1){
            int p = pi - l;
            int pm = ((p%8)+8)%8;
            float wr = CW8[pm], wi = SW8[pm];
            for (int ib = 0; ib < 3; ++ib){
                float d = fb[O_D1SG + (l*3+ib)*11 + pi];
                float er = 1.f, ei = 0.f, sx = 0.f, sy = 0.f;
                #pragma unroll
                for (int ia = 0; ia < 8; ++ia){
                    float w = w1[o*24 + ib*8 + ia];
                    sx += w*er; sy += w*ei;
                    float nr = er*wr - ei*wi; ei = er*wi + ei*wr; er = nr;
                }
                acc.x += d*sx; acc.y += d*sy;
            }
        }
        cb[O_CY1 + (o*6+l)*11 + pi] = acc;
        return;
    }
    gid -= 528;
    if (gid < 6336){   // D1S [66cell][8l][12k], sorted cells
        int k = gid%12; int t = gid/12; int l = t%8; int cell = t/8;
        int L, m, p; cell_decode(cell, L, m, p);
        float v = 0.f;
        if (l < 6 && l >= L){
            double beta = DPI*(2*k+1)/24.0;
            v = (float)dev_wig(l, m, p, beta);
        }
        fb[O_D1S+gid] = v; return;
    }
    gid -= 6336;
    if (gid < 360){    // DG [30slot][12k]
        int k = gid%12; int slot = gid/12;
        int lm = slot/5, qt = slot%5;
        int l = lm==0?0:(lm<3?1:2);
        int m = lm==0?0:(lm<3?lm-1:lm-3);
        float v = 0.f;
        if (qt < 2*l+1){
            double beta = DPI*(2*k+1)/24.0;
            v = (float)(dev_wig(l, m, qt-l, beta) * dev_qw(6, beta));
        }
        fb[O_DG+gid] = v; return;
    }
    gid -= 360;
    if (gid < 360){    // D2P [15(m,pi)][6k][4lp]
        int lp = gid%4; int t = gid/4; int k = t%6; int cell = t/6;
        int m = cell/5, pi = cell%5, p = pi-2, ap = p<0?-p:p;
        float v = 0.f;
        if (lp < 3 && lp >= m && lp >= ap){
            double beta = DPI*(2*k+1)/12.0;
            v = (float)dev_wig(lp, m, p, beta);
        }
        fb[O_D2P+gid] = v; return;
    }
}

// ---------------- s2 fft: x[2048,1,20,20] -> XS[n][l^2+mi] ----------------
__global__ __launch_bounds__(64) void k_s2fft(const float* __restrict__ x, const float* __restrict__ fb,
                                              c32* __restrict__ XS){
    __shared__ float xsh[400];
    __shared__ c32 F1[20][6];
    int n = blockIdx.x, tid = threadIdx.x;
    for (int i = tid; i < 400; i += 64) xsh[i] = x[n*400 + i];
    __syncthreads();
    for (int i = tid; i < 120; i += 64){
        int k = i/6, m = i%6;
        float wr = CW20_[m], wi = -SW20_[m];   // e^{-2pi i m/20}
        float er = 1.f, ei = 0.f, ax = 0.f, ay = 0.f;
        const float* row = xsh + k*20;
        #pragma unroll
        for (int a = 0; a < 20; ++a){
            float v = row[a];
            ax += v*er; ay += v*ei;
            float nr = er*wr - ei*wi; ei = er*wi + ei*wr; er = nr;
        }
        F1[k][m] = make_float2(ax, ay);
    }
    __syncthreads();
    if (tid < 36){
        int l = 0; while ((l+1)*(l+1) <= tid) ++l;
        int mi = tid - l*l; int m = mi - l;
        c32 acc = make_float2(0.f,0.f);
        for (int k = 0; k < 20; ++k){
            float d = fb[O_S2D + (l*20+k)*11 + mi];
            c32 F = (m >= 0) ? F1[k][m] : make_float2(F1[k][-m].x, -F1[k][-m].y);
            acc.x += d*F.x; acc.y += d*F.y;
        }
        XS[n*36 + tid] = acc;
    }
}

// ---------------- layer 1 megakernel: per (n,o) ----------------
__global__ __launch_bounds__(256) void k_layer1(const c32* __restrict__ cb, const float* __restrict__ fb,
                                                const float* __restrict__ b1, c32* __restrict__ xs2p){
    __shared__ c32 xs_sh[36];
    __shared__ c32 u1[864];   // zps[6][66] -> T[6m][12g][12k]
    __shared__ c32 u2[936];   // S[66mp][12k] -> h float[12g][12a][13kpad]
    __shared__ c32 Gg[432];   // [3mg][12a][12k]
    __shared__ c32 Gs[180];   // [5mai][3mg][12k]
    int tid = threadIdx.x;
    int n = blockIdx.x >> 3, o = blockIdx.x & 7;
    float bias = b1[o];
    if (tid < 36) xs_sh[tid] = cb[O_XS + n*36 + tid];
    __syncthreads();

    // A: zps[l][mp] = (2l+1) * xs_l(m) * conjY1_l(p), m>=0, zero-padded
    for (int c = tid; c < 396; c += 256){
        int l = c/66, mp = c - l*66, m = mp/11, pi = mp - m*11;
        int p = pi - 5, ap = p < 0 ? -p : p;
        c32 v = make_float2(0.f, 0.f);
        if (m <= l && ap <= l){
            c32 a = xs_sh[l*l + l + m];
            c32 b = cb[O_CY1 + o*66 + l*11 + p + l];
            float f = (float)(2*l+1);
            v.x = f*(a.x*b.x - a.y*b.y); v.y = f*(a.x*b.y + a.y*b.x);
        }
        u1[c] = v;
    }
    __syncthreads();

    // B: S[mp][k] = sum_{l>=L} d1s * zps ; lane = (sorted cell, k-half), valid-l only
    if (tid < 132){
        int cell = tid >> 1, kh = tid & 1;
        int L, m, p; cell_decode(cell, L, m, p);
        int mp = m*11 + p + 5;
        c32 acc[6];
        #pragma unroll
        for (int j = 0; j < 6; ++j) acc[j] = make_float2(0.f,0.f);
        for (int l = L; l < 6; ++l){
            c32 z = u1[l*66 + mp];
            const float* dp = fb + O_D1S + (cell*8 + l)*12 + kh*6;
            #pragma unroll
            for (int j = 0; j < 6; ++j){
                float d = dp[j];
                acc[j].x += d*z.x; acc[j].y += d*z.y;
            }
        }
        #pragma unroll
        for (int j = 0; j < 6; ++j) u2[mp*12 + kh*6 + j] = acc[j];
    }
    __syncthreads();

    // C: T[m][g][k] = sum_p S w12^{pg}; +-p Hermitian pairing AND g<->g+6 parity
    if (tid < 72){
        int m = tid/12, k = tid - m*12;
        c32 S0 = u2[(m*11+5)*12 + k];
        c32 E[5], O[5];
        #pragma unroll
        for (int p = 1; p <= 5; ++p){
            c32 a = u2[(m*11+5+p)*12 + k], b = u2[(m*11+5-p)*12 + k];
            E[p-1] = make_float2(a.x+b.x, a.y+b.y);
            O[p-1] = make_float2(a.x-b.x, a.y-b.y);
        }
        #pragma unroll
        for (int g = 0; g < 6; ++g){
            float vex=0.f, vey=0.f, vox=0.f, voy=0.f;
            #pragma unroll
            for (int p = 1; p <= 5; ++p){
                const float cc = CW12[M12(p*g)], ss = SW12[M12(p*g)];
                float vx = E[p-1].x*cc - O[p-1].y*ss;
                float vy = E[p-1].y*cc + O[p-1].x*ss;
                if (p & 1){ vox += vx; voy += vy; } else { vex += vx; vey += vy; }
            }
            float tex = S0.x + vex, tey = S0.y + vey;
            u1[(m*12+g)*12 + k]   = make_float2(tex + vox, tey + voy);
            u1[(m*12+g+6)*12 + k] = make_float2(tex - vox, tey - voy);
        }
    }
    __syncthreads();

    // D: h[g][a][k] = ReLU( T0 + 2*sum_{m>0} Re(Tm w12^{ma}) + bias ), a-parity shared
    float* hh = (float*)u2;   // layout [12g][12a][13k]
    if (tid < 144){
        int g = tid/12, k = tid - g*12;
        c32 t1 = u1[(1*12+g)*12+k], t2 = u1[(2*12+g)*12+k], t3 = u1[(3*12+g)*12+k];
        c32 t4 = u1[(4*12+g)*12+k], t5 = u1[(5*12+g)*12+k];
        float base = u1[(0*12+g)*12+k].x + bias;
        #pragma unroll
        for (int a = 0; a < 6; ++a){
            float od = t1.x*CW12[M12(1*a)] - t1.y*SW12[M12(1*a)]
                     + t3.x*CW12[M12(3*a)] - t3.y*SW12[M12(3*a)]
                     + t5.x*CW12[M12(5*a)] - t5.y*SW12[M12(5*a)];
            float ev = t2.x*CW12[M12(2*a)] - t2.y*SW12[M12(2*a)]
                     + t4.x*CW12[M12(4*a)] - t4.y*SW12[M12(4*a)];
            float h0 = base + 2.f*(ev+od);
            float h1 = base + 2.f*(ev-od);
            hh[(g*12+a)*13+k]     = h0 > 0.f ? h0 : 0.f;
            hh[(g*12+a+6)*13+k]   = h1 > 0.f ? h1 : 0.f;
        }
    }
    __syncthreads();

    // E: Gg[mg][a][k] = sum_g h e^{-2pi i mg g/12}, mg=0 real-sum special case
    if (tid < 144){
        int a = tid/12, k = tid - a*12;
        float hv[12];
        #pragma unroll
        for (int g = 0; g < 12; ++g) hv[g] = hh[(g*12+a)*13+k];
        float s0 = 0.f;
        #pragma unroll
        for (int g = 0; g < 12; ++g) s0 += hv[g];
        Gg[a*12+k] = make_float2(s0, 0.f);
        #pragma unroll
        for (int mg = 1; mg < 3; ++mg){
            float ax = 0.f, ay = 0.f;
            #pragma unroll
            for (int g = 0; g < 12; ++g){
                const int tt = M12(mg*g);
                ax += hv[g]*CW12[tt]; ay -= hv[g]*SW12[tt];
            }
            Gg[(mg*12+a)*12+k] = make_float2(ax, ay);
        }
    }
    __syncthreads();

    // F: Gs[mai][mg][k] = sum_a Gg e^{-2pi i ma a/12}; a-parity + +-ma conjugate pairing
    if (tid < 108){
        int j = tid/36, r = tid - j*36, mg = r/12, k = r - mg*12;
        const c32* gp = Gg + mg*144 + k;
        if (j == 0){             // ma = 0
            float sx = 0.f, sy = 0.f;
            #pragma unroll
            for (int a = 0; a < 6; ++a){
                c32 xa = gp[a*12], ya = gp[(a+6)*12];
                sx += xa.x + ya.x; sy += xa.y + ya.y;
            }
            Gs[(2*3+mg)*12+k] = make_float2(sx, sy);
        } else if (j == 1){      // ma = +-1 (odd: u = gv[a]-gv[a+6])
            float Cx=0.f,Cy=0.f,Sx=0.f,Sy=0.f;
            #pragma unroll
            for (int a = 0; a < 6; ++a){
                c32 xa = gp[a*12], ya = gp[(a+6)*12];
                float ux = xa.x - ya.x, uy = xa.y - ya.y;
                const float cc = CW12[a], ss = SW12[a];
                Cx += ux*cc; Cy += uy*cc;
                Sx += ux*ss; Sy += uy*ss;
            }
            Gs[(3*3+mg)*12+k] = make_float2(Cx + Sy, Cy - Sx);  // ma=+1
            Gs[(1*3+mg)*12+k] = make_float2(Cx - Sy, Cy + Sx);  // ma=-1
        } else {                 // ma = +-2 (even: u = gv[a]+gv[a+6])
            float Cx=0.f,Cy=0.f,Sx=0.f,Sy=0.f;
            #pragma unroll
            for (int a = 0; a < 6; ++a){
                c32 xa = gp[a*12], ya = gp[(a+6)*12];
                float ux = xa.x + ya.x, uy = xa.y + ya.y;
                const float cc = CW12[M12(2*a)], ss = SW12[M12(2*a)];
                Cx += ux*cc; Cy += uy*cc;
                Sx += ux*ss; Sy += uy*ss;
            }
            Gs[(4*3+mg)*12+k] = make_float2(Cx + Sy, Cy - Sx);  // ma=+2
            Gs[(0*3+mg)*12+k] = make_float2(Cx - Sy, Cy + Sx);  // ma=-2
        }
    }
    __syncthreads();

    // G: xs2p slot(lm,qt): sum_k dG * G(k,m,q)
    if (tid < 30){
        int lm = tid/5, qt = tid - lm*5;
        int l = lm==0?0:(lm<3?1:2);
        int m = lm==0?0:(lm<3?lm-1:lm-3);
        c32 acc = make_float2(0.f,0.f);
        if (qt < 2*l+1){
            int q = qt - l;
            #pragma unroll
            for (int k = 0; k < 12; ++k){
                float d = fb[O_DG + tid*12 + k];
                c32 gvv;
                if (q >= 0) gvv = Gs[((m+2)*3 + q)*12 + k];
                else { c32 w = Gs[((2-m)*3 + (-q))*12 + k]; gvv = make_float2(w.x, -w.y); }
                acc.x += d*gvv.x; acc.y += d*gvv.y;
            }
        }
        xs2p[(n*8+o)*30 + tid] = acc;
    }
}

// ---------------- layer 2 + integrate: block per 4 n, all 16 o ----------------
__global__ __launch_bounds__(256) void k_layer2(const c32* __restrict__ cb, const float* __restrict__ fb,
                                                const float* __restrict__ b2, float* __restrict__ feat){
    __shared__ c32 xs2sh[960];    // [4nl][8i][6lm][5qt]
    __shared__ c32 zp2[4][384];   // [nl][16o][24cellpad]
    __shared__ c32 T2[1728];      // [16o][6k][3m][6g], reused per nl
    __shared__ float part[576];   // [16o][36(k,g)]
    int tid = threadIdx.x, n0 = blockIdx.x*4;
    for (int c = tid; c < 960; c += 256) xs2sh[c] = cb[O_XS2P + n0*240 + c];
    __syncthreads();

    for (int c = tid; c < 1408; c += 256){
        int nl = c/352, cc = c - nl*352, o = cc/22, cell = cc - o*22;
        int l, lm;
        if (cell == 0){ l=0; lm=0; }
        else if (cell < 7){ l=1; lm=1+(cell-1)/3; }
        else { l=2; lm=3+(cell-7)/5; }
        const c32* cy = cb + O_CY2P + (o*22+cell)*40;
        const c32* xv0 = xs2sh + nl*240;
        c32 acc = make_float2(0.f,0.f);
        #pragma unroll
        for (int i = 0; i < 8; ++i){
            #pragma unroll
            for (int qt = 0; qt < 5; ++qt){
                c32 xv = xv0[(i*6+lm)*5 + qt];
                c32 yv = cy[i*5+qt];
                acc.x += xv.x*yv.x - xv.y*yv.y;
                acc.y += xv.x*yv.y + xv.y*yv.x;
            }
        }
        float f = (float)(2*l+1);
        zp2[nl][o*24+cell] = make_float2(f*acc.x, f*acc.y);
    }
    __syncthreads();

    for (int nl = 0; nl < 4; ++nl){
        for (int c = tid; c < 288; c += 256){
            int o = c/18, r = c - o*18, k = r/3, m = r - k*3;
            c32 s2v[5];
            #pragma unroll
            for (int pi = 0; pi < 5; ++pi){
                const int p = pi-2; const int ap = p<0?-p:p;
                c32 acc = make_float2(0.f,0.f);
                #pragma unroll
                for (int l = 0; l < 3; ++l){
                    if (l >= ap){
                        float d = fb[O_D2P + ((m*5+pi)*6+k)*4 + l];
                        int cell = (l==0) ? 0 : ((l==1) ? 1+m*3+(p+1) : 7+m*5+(p+2));
                        c32 z = zp2[nl][o*24+cell];
                        acc.x += d*z.x; acc.y += d*z.y;
                    }
                }
                s2v[pi] = acc;
            }
            #pragma unroll
            for (int g = 0; g < 6; ++g){
                c32 t = make_float2(0.f,0.f);
                #pragma unroll
                for (int pi = 0; pi < 5; ++pi){
                    const int tt = M6((pi-2)*g);
                    cmadd(t, s2v[pi], CW6[tt], SW6[tt]);
                }
                T2[((o*6+k)*3+m)*6+g] = t;
            }
        }
        __syncthreads();
        for (int c = tid; c < 576; c += 256){
            int o = c/36, r = c - o*36, k = r/6, g = r - k*6;
            c32 t0 = T2[((o*6+k)*3+0)*6+g];
            c32 t1 = T2[((o*6+k)*3+1)*6+g];
            c32 t2 = T2[((o*6+k)*3+2)*6+g];
            float base = t0.x + b2[o];
            float s = 0.f;
            #pragma unroll
            for (int a = 0; a < 6; ++a){
                float h = base + 2.f*(t1.x*CW6[M6(a)]   - t1.y*SW6[M6(a)])
                               + 2.f*(t2.x*CW6[M6(2*a)] - t2.y*SW6[M6(2*a)]);
                s += h > 0.f ? h : 0.f;
            }
            part[c] = s * fb[O_WINT + k];
        }
        __syncthreads();
        if (tid < 16){
            float s = 0.f;
            #pragma unroll
            for (int j = 0; j < 36; ++j) s += part[tid*36+j];
            feat[(n0+nl)*16+tid] = s * (1.f/36.f);
        }
        __syncthreads();
    }
}

// ---------------- pool + head fused: one block ----------------
__global__ __launch_bounds__(256) void k_poolhead(const float* __restrict__ feat,
                                                  const float* __restrict__ w_out,
                                                  const float* __restrict__ bias_out,
                                                  float* __restrict__ out){
    __shared__ float red[256];
    __shared__ float pool_s[64];
    int tid = threadIdx.x;
    int pair = tid >> 2, chunk = tid & 3;    // pair = b*16+o
    int b = pair >> 4, o = pair & 15;
    float m = -3.4e38f;
    for (int j = 0; j < 128; ++j){
        int pt = chunk*128 + j;
        m = fmaxf(m, feat[(b*512+pt)*16 + o]);
    }
    red[tid] = m;
    __syncthreads();
    if (tid < 64){
        pool_s[tid] = fmaxf(fmaxf(red[tid*4], red[tid*4+1]),
                            fmaxf(red[tid*4+2], red[tid*4+3]));
    }
    __syncthreads();
    if (tid < 40){
        int bb = tid/10, jj = tid%10;
        float s = bias_out[jj];
        #pragma unroll
        for (int oo = 0; oo < 16; ++oo) s += pool_s[bb*16+oo]*w_out[jj*16+oo];
        out[tid] = s;
    }
}

extern "C" void kernel_launch(void* const* d_in, const int* in_sizes, int n_in,
                              void* d_out, int out_size, void* d_ws, size_t ws_size,
                              hipStream_t stream){
    const float* x        = (const float*)d_in[0];
    const float* w1       = (const float*)d_in[1];
    const float* b1       = (const float*)d_in[2];
    const float* w2       = (const float*)d_in[3];
    const float* b2       = (const float*)d_in[4];
    const float* w_out    = (const float*)d_in[5];
    const float* bias_out = (const float*)d_in[6];
    float* out = (float*)d_out;

    c32*   cb = (c32*)d_ws;
    float* fb = (float*)(cb + N_C32_TOTAL);
    float* feat = fb + O_FEAT;

    k_setup_pre<<<2, 256, 0, stream>>>(fb);                        // 429 items
    k_setup_main<<<163, 256, 0, stream>>>(cb, fb, w1, w2);         // 128 CY2P blocks + 8904 items
    k_s2fft<<<2048, 64, 0, stream>>>(x, fb, cb + O_XS);
    k_layer1<<<2048*8, 256, 0, stream>>>(cb, fb, b1, cb + O_XS2P);
    k_layer2<<<512, 256, 0, stream>>>(cb, fb, b2, feat);
    k_poolhead<<<1, 256, 0, stream>>>(feat, w_out, bias_out, out);
}

// Round 6
// 180.155 us; speedup vs baseline: 1.1032x; 1.1032x over previous
//
#include <hip/hip_runtime.h>
#include <cmath>

typedef float2 c32;

__device__ __forceinline__ void cmadd(c32& acc, c32 a, float cr, float ci){
    acc.x += a.x*cr - a.y*ci;
    acc.y += a.x*ci + a.y*cr;
}

__host__ __device__ constexpr int M12(int x){ return ((x%12)+12)%12; }
__host__ __device__ constexpr int M6(int x){ return ((x%6)+6)%6; }

#define SQ32 0.86602540378443864676f
#define RT22 0.70710678118654752440f
static constexpr float CW12[12] = {1.f, SQ32, 0.5f, 0.f, -0.5f, -SQ32, -1.f, -SQ32, -0.5f, 0.f, 0.5f, SQ32};
static constexpr float SW12[12] = {0.f, 0.5f, SQ32, 1.f, SQ32, 0.5f, 0.f, -0.5f, -SQ32, -1.f, -SQ32, -0.5f};
static constexpr float CW6[6] = {1.f, 0.5f, -0.5f, -1.f, -0.5f, 0.5f};
static constexpr float SW6[6] = {0.f, SQ32, SQ32, 0.f, -SQ32, -SQ32};
static constexpr float CW8[8] = {1.f, RT22, 0.f, -RT22, -1.f, -RT22, 0.f, RT22};
static constexpr float SW8[8] = {0.f, RT22, 1.f, RT22, 0.f, -RT22, -1.f, -RT22};
static constexpr float CW20_[6] = {1.f, 0.95105651629515357212f, 0.80901699437494742410f,
                                   0.58778525229247312917f, 0.30901699437494742410f, 0.f};
static constexpr float SW20_[6] = {0.f, 0.30901699437494742410f, 0.58778525229247312917f,
                                   0.80901699437494742410f, 0.95105651629515357212f, 1.f};

// ---------------- workspace layout ----------------
// float2 region
#define O_CY1  0                   // [8o][66]
#define O_CY2P 528                 // [16o][22cell][8i][5qt]
#define O_XS   (O_CY2P + 14080)    // [2048n][36]
#define O_XS2P (O_XS + 73728)      // [2048n][8i][30slot]
#define N_C32_TOTAL (O_XS2P + 2048*8*30)

// float region
#define O_S2D  0                   // [6l][20k][11mi]
#define O_D1SG 1320                // [6l][3ib][11pi]
#define O_D2SG 1518                // [3l][3ib][5pi][5qi]
#define O_WINT 1743                // [6]
#define O_D1S  1752                // [66cell][8l][12k] sorted-by-lmin cells
#define O_DG   (O_D1S + 6336)      // [30slot][12k]
#define O_D2P  (O_DG + 360)        // [15(m,pi)][6k][4lp]
#define O_FEAT (O_D2P + 360)       // [2048n][16o]
#define O_POOL (O_FEAT + 32768)    // [64]

#define DPI 3.14159265358979323846

// sorted cell enumeration: cells grouped by L = max(m,|p|), m>=0
__device__ __forceinline__ void cell_decode(int c, int& L, int& m, int& p){
    int base;
    if (c < 1){ L=0; base=0; } else if (c < 6){ L=1; base=1; }
    else if (c < 15){ L=2; base=6; } else if (c < 28){ L=3; base=15; }
    else if (c < 45){ L=4; base=28; } else { L=5; base=45; }
    int r = c - base;
    if (r < 2*L){ m = r>>1; p = (r&1)? L : -L; }
    else { m = L; p = (r - 2*L) - L; }
}

// ---------------- Wigner-d via factorial table ----------------
static constexpr double FCT[13] = {1.,1.,2.,6.,24.,120.,720.,5040.,40320.,
                                   362880.,3628800.,39916800.,479001600.};

__device__ __forceinline__ double dipow(double b, int e){
    double r = 1.0;
    while (e){ if (e & 1) r *= b; b *= b; e >>= 1; }
    return r;
}

__device__ double dev_wig(int l, int mp, int m, double beta){
    int k0 = max(0, m - mp), k1 = min(l + m, l - mp);
    double c = cos(0.5*beta), s = sin(0.5*beta);
    double fnum = sqrt(FCT[l+mp]*FCT[l-mp]*FCT[l+m]*FCT[l-m]);
    double acc = 0.0;
    for (int k = k0; k <= k1; ++k){
        double t = fnum / (FCT[l+m-k]*FCT[k]*FCT[mp-m+k]*FCT[l-mp-k])
                 * dipow(c, 2*l-2*k+m-mp) * dipow(s, mp-m+2*k);
        acc += ((mp-m+k) & 1) ? -t : t;
    }
    return acc;
}

__device__ double dev_qw(int b, double beta){
    double s = 0.0;
    for (int j = 0; j < b; ++j) s += sin((2.0*j+1.0)*beta)/(2.0*j+1.0);
    return (2.0/b)*sin(beta)*s;
}

// ---------------- setup pre: D1SG, D2SG, WINT ----------------
__global__ __launch_bounds__(256) void k_setup_pre(float* fb){
    int gid = blockIdx.x*256 + threadIdx.x;
    if (gid < 198){    // D1SG [6l][3ib][11pi]
        int pi = gid%11; int t = gid/11; int ib = t%3; int l = t/3;
        float v = 0.f;
        if (pi < 2*l+1){ double beta = (ib+1)*DPI/24.0; v = (float)dev_wig(l, pi-l, 0, beta); }
        fb[O_D1SG+gid] = v; return;
    }
    gid -= 198;
    if (gid < 225){    // D2SG [3l][3ib][5pi][5qi]
        int qi = gid%5; int t = gid/5; int pi = t%5; t /= 5; int ib = t%3; int l = t/3;
        float v = 0.f;
        if (pi < 2*l+1 && qi < 2*l+1){ double beta = (ib+1)*DPI/24.0; v = (float)dev_wig(l, pi-l, qi-l, beta); }
        fb[O_D2SG+gid] = v; return;
    }
    gid -= 225;
    if (gid < 6){ double beta = DPI*(2*gid+1)/12.0; fb[O_WINT+gid] = (float)dev_qw(3, beta); return; }
}

// ---------------- setup main: blocks 0..127 = CY2P per (o,i); blocks 128+ = item pool ----------------
__global__ __launch_bounds__(256) void k_setup_main(c32* cb, float* fb,
                                                    const float* __restrict__ w1,
                                                    const float* __restrict__ w2){
    __shared__ float wsh[144];
    __shared__ c32 W1s[3][8][5];
    __shared__ c32 Rs[3][5][5];
    int bid = blockIdx.x, tid = threadIdx.x;
    if (bid < 128){
        int o = bid >> 3, i = bid & 7;
        for (int c = tid; c < 144; c += 256) wsh[c] = w2[(i*16+o)*144 + c];
        __syncthreads();
        for (int c = tid; c < 120; c += 256){
            int ib = c/40, r = c%40, ia = r/5, qi = r%5;
            int q = qi - 2; int qm = ((q%6)+6)%6;
            float wr = CW6[qm], wi = SW6[qm];
            float er = 1.f, ei = 0.f, sx = 0.f, sy = 0.f;
            const float* wrow = wsh + ib*48 + ia*6;
            #pragma unroll
            for (int ig = 0; ig < 6; ++ig){
                float w = wrow[ig];
                sx += w*er; sy += w*ei;
                float nr = er*wr - ei*wi; ei = er*wi + ei*wr; er = nr;
            }
            W1s[ib][ia][qi] = make_float2(sx, sy);
        }
        __syncthreads();
        for (int c = tid; c < 75; c += 256){
            int ib = c/25, r = c%25, pi = r/5, qi = r%5;
            int p = pi - 2; int pm = ((p%8)+8)%8;
            float wr = CW8[pm], wi = SW8[pm];
            float er = 1.f, ei = 0.f;
            c32 acc = make_float2(0.f,0.f);
            #pragma unroll
            for (int ia = 0; ia < 8; ++ia){
                c32 wv = W1s[ib][ia][qi];
                acc.x += wv.x*er - wv.y*ei;
                acc.y += wv.x*ei + wv.y*er;
                float nr = er*wr - ei*wi; ei = er*wi + ei*wr; er = nr;
            }
            Rs[ib][pi][qi] = acc;
        }
        __syncthreads();
        for (int c = tid; c < 110; c += 256){
            int cell = c/5, qt = c%5;
            int l, p;
            if (cell == 0){ l=0; p=0; }
            else if (cell < 7){ l=1; p=(cell-1)%3 - 1; }
            else { l=2; p=(cell-7)%5 - 2; }
            c32 acc = make_float2(0.f,0.f);
            if (qt < 2*l+1){
                int q = qt - l;
                #pragma unroll
                for (int ib = 0; ib < 3; ++ib){
                    float d = fb[O_D2SG + (l*3+ib)*25 + (p+l)*5 + (q+l)];
                    c32 rv = Rs[ib][p+2][q+2];
                    acc.x += d*rv.x; acc.y += d*rv.y;
                }
            }
            cb[O_CY2P + ((o*22+cell)*8 + i)*5 + qt] = acc;
        }
        return;
    }
    int gid = (bid-128)*256 + tid;
    if (gid < 1320){   // S2D [6l][20k][11mi]
        int mi = gid%11; int t = gid/11; int k = t%20; int l = t/20;
        float v = 0.f;
        if (mi < 2*l+1){
            double beta = DPI*(2*k+1)/40.0;
            v = (float)(dev_wig(l, mi-l, 0, beta) * dev_qw(10, beta));
        }
        fb[O_S2D+gid] = v; return;
    }
    gid -= 1320;
    if (gid < 528){    // CY1 [8o][6l][11pi]
        int pi = gid%11; int t = gid/11; int l = t%6; int o = t/6;
        c32 acc = make_float2(0.f,0.f);
        if (pi < 2*l+1){
            int p = pi - l;
            int pm = ((p%8)+8)%8;
            float wr = CW8[pm], wi = SW8[pm];
            for (int ib = 0; ib < 3; ++ib){
                float d = fb[O_D1SG + (l*3+ib)*11 + pi];
                float er = 1.f, ei = 0.f, sx = 0.f, sy = 0.f;
                #pragma unroll
                for (int ia = 0; ia < 8; ++ia){
                    float w = w1[o*24 + ib*8 + ia];
                    sx += w*er; sy += w*ei;
                    float nr = er*wr - ei*wi; ei = er*wi + ei*wr; er = nr;
                }
                acc.x += d*sx; acc.y += d*sy;
            }
        }
        cb[O_CY1 + (o*6+l)*11 + pi] = acc;
        return;
    }
    gid -= 528;
    if (gid < 6336){   // D1S [66cell][8l][12k]
        int k = gid%12; int t = gid/12; int l = t%8; int cell = t/8;
        int L, m, p; cell_decode(cell, L, m, p);
        float v = 0.f;
        if (l < 6 && l >= L){
            double beta = DPI*(2*k+1)/24.0;
            v = (float)dev_wig(l, m, p, beta);
        }
        fb[O_D1S+gid] = v; return;
    }
    gid -= 6336;
    if (gid < 360){    // DG [30slot][12k]
        int k = gid%12; int slot = gid/12;
        int lm = slot/5, qt = slot%5;
        int l = lm==0?0:(lm<3?1:2);
        int m = lm==0?0:(lm<3?lm-1:lm-3);
        float v = 0.f;
        if (qt < 2*l+1){
            double beta = DPI*(2*k+1)/24.0;
            v = (float)(dev_wig(l, m, qt-l, beta) * dev_qw(6, beta));
        }
        fb[O_DG+gid] = v; return;
    }
    gid -= 360;
    if (gid < 360){    // D2P [15(m,pi)][6k][4lp]
        int lp = gid%4; int t = gid/4; int k = t%6; int cell = t/6;
        int m = cell/5, pi = cell%5, p = pi-2, ap = p<0?-p:p;
        float v = 0.f;
        if (lp < 3 && lp >= m && lp >= ap){
            double beta = DPI*(2*k+1)/12.0;
            v = (float)dev_wig(lp, m, p, beta);
        }
        fb[O_D2P+gid] = v; return;
    }
}

// ---------------- s2 fft: 4 n per block ----------------
__global__ __launch_bounds__(256) void k_s2fft(const float* __restrict__ x, const float* __restrict__ fb,
                                               c32* __restrict__ XS){
    __shared__ float xsh[1600];      // [4nl][400]
    __shared__ c32 F1[4][20][6];
    int n0 = blockIdx.x*4, tid = threadIdx.x;
    for (int i = tid; i < 1600; i += 256) xsh[i] = x[n0*400 + i];
    __syncthreads();
    for (int i = tid; i < 480; i += 256){
        int nl = i/120, r = i - nl*120, k = r/6, m = r - k*6;
        float wr = CW20_[m], wi = -SW20_[m];   // e^{-2pi i m/20}
        float er = 1.f, ei = 0.f, ax = 0.f, ay = 0.f;
        const float* row = xsh + nl*400 + k*20;
        #pragma unroll
        for (int a = 0; a < 20; ++a){
            float v = row[a];
            ax += v*er; ay += v*ei;
            float nr = er*wr - ei*wi; ei = er*wi + ei*wr; er = nr;
        }
        F1[nl][k][m] = make_float2(ax, ay);
    }
    __syncthreads();
    if (tid < 144){
        int nl = tid/36, t = tid - nl*36;
        int l = 0; while ((l+1)*(l+1) <= t) ++l;
        int mi = t - l*l; int m = mi - l;
        c32 acc = make_float2(0.f,0.f);
        for (int k = 0; k < 20; ++k){
            float d = fb[O_S2D + (l*20+k)*11 + mi];
            c32 F = (m >= 0) ? F1[nl][k][m] : make_float2(F1[nl][k][-m].x, -F1[nl][k][-m].y);
            acc.x += d*F.x; acc.y += d*F.y;
        }
        XS[(n0+nl)*36 + t] = acc;
    }
}

// ---------------- layer 1: 2 (n,o) units per block, lanes split 128/128 ----------------
__global__ __launch_bounds__(256) void k_layer1(const c32* __restrict__ cb, const float* __restrict__ fb,
                                                const float* __restrict__ b1, c32* __restrict__ xs2p){
    __shared__ c32 xs_sh[36];
    __shared__ c32 u1[2][864];   // zps[6][66] -> T[6m][12g][12k] -> (alias) Gg[432] + Gs[180]
    __shared__ c32 u2[2][936];   // S[66mp][12k] -> h float[12g][12a][13kpad]
    int tid = threadIdx.x;
    int half = tid >> 7, r = tid & 127;
    int n = blockIdx.x >> 2, oh = blockIdx.x & 3;
    int o = oh*2 + half;
    float bias = b1[o];
    if (tid < 36) xs_sh[tid] = cb[O_XS + n*36 + tid];
    __syncthreads();

    // A: zps[l][mp] = (2l+1) * xs_l(m) * conjY1_l(p), m>=0, zero-padded
    for (int c = r; c < 396; c += 128){
        int l = c/66, mp = c - l*66, m = mp/11, pi = mp - m*11;
        int p = pi - 5, ap = p < 0 ? -p : p;
        c32 v = make_float2(0.f, 0.f);
        if (m <= l && ap <= l){
            c32 a = xs_sh[l*l + l + m];
            c32 b = cb[O_CY1 + o*66 + l*11 + p + l];
            float f = (float)(2*l+1);
            v.x = f*(a.x*b.x - a.y*b.y); v.y = f*(a.x*b.y + a.y*b.x);
        }
        u1[half][c] = v;
    }
    __syncthreads();

    // B: S[mp][k] = sum_{l>=L} d1s * zps ; lane = sorted cell, all 12 k in regs
    if (r < 66){
        int cell = r;
        int L, m, p; cell_decode(cell, L, m, p);
        int mp = m*11 + p + 5;
        c32 acc[12];
        #pragma unroll
        for (int j = 0; j < 12; ++j) acc[j] = make_float2(0.f,0.f);
        for (int l = L; l < 6; ++l){
            c32 z = u1[half][l*66 + mp];
            const float* dp = fb + O_D1S + (cell*8 + l)*12;
            #pragma unroll
            for (int j = 0; j < 12; ++j){
                float d = dp[j];
                acc[j].x += d*z.x; acc[j].y += d*z.y;
            }
        }
        #pragma unroll
        for (int j = 0; j < 12; ++j) u2[half][mp*12 + j] = acc[j];
    }
    __syncthreads();

    // C: T[m][g][k] = sum_p S w12^{pg}; +-p Hermitian pairing AND g<->g+6 parity
    if (r < 72){
        int m = r/12, k = r - m*12;
        c32 S0 = u2[half][(m*11+5)*12 + k];
        c32 E[5], O[5];
        #pragma unroll
        for (int p = 1; p <= 5; ++p){
            c32 a = u2[half][(m*11+5+p)*12 + k], b = u2[half][(m*11+5-p)*12 + k];
            E[p-1] = make_float2(a.x+b.x, a.y+b.y);
            O[p-1] = make_float2(a.x-b.x, a.y-b.y);
        }
        #pragma unroll
        for (int g = 0; g < 6; ++g){
            float vex=0.f, vey=0.f, vox=0.f, voy=0.f;
            #pragma unroll
            for (int p = 1; p <= 5; ++p){
                const float cc = CW12[M12(p*g)], ss = SW12[M12(p*g)];
                float vx = E[p-1].x*cc - O[p-1].y*ss;
                float vy = E[p-1].y*cc + O[p-1].x*ss;
                if (p & 1){ vox += vx; voy += vy; } else { vex += vx; vey += vy; }
            }
            float tex = S0.x + vex, tey = S0.y + vey;
            u1[half][(m*12+g)*12 + k]   = make_float2(tex + vox, tey + voy);
            u1[half][(m*12+g+6)*12 + k] = make_float2(tex - vox, tey - voy);
        }
    }
    __syncthreads();

    // D: h[g][a][k] = ReLU( T0 + 2*sum_{m>0} Re(Tm w12^{ma}) + bias ), a-parity shared
    float* hh = (float*)u2[half];   // [12g][12a][13k]
    for (int c = r; c < 144; c += 128){
        int g = c/12, k = c - g*12;
        c32 t1 = u1[half][(1*12+g)*12+k], t2 = u1[half][(2*12+g)*12+k], t3 = u1[half][(3*12+g)*12+k];
        c32 t4 = u1[half][(4*12+g)*12+k], t5 = u1[half][(5*12+g)*12+k];
        float base = u1[half][(0*12+g)*12+k].x + bias;
        #pragma unroll
        for (int a = 0; a < 6; ++a){
            float od = t1.x*CW12[M12(1*a)] - t1.y*SW12[M12(1*a)]
                     + t3.x*CW12[M12(3*a)] - t3.y*SW12[M12(3*a)]
                     + t5.x*CW12[M12(5*a)] - t5.y*SW12[M12(5*a)];
            float ev = t2.x*CW12[M12(2*a)] - t2.y*SW12[M12(2*a)]
                     + t4.x*CW12[M12(4*a)] - t4.y*SW12[M12(4*a)];
            float h0 = base + 2.f*(ev+od);
            float h1 = base + 2.f*(ev-od);
            hh[(g*12+a)*13+k]     = h0 > 0.f ? h0 : 0.f;
            hh[(g*12+a+6)*13+k]   = h1 > 0.f ? h1 : 0.f;
        }
    }
    __syncthreads();

    // E: Gg[mg][a][k] = sum_g h e^{-2pi i mg g/12}; Gg aliases dead T region of u1
    c32* Gg = u1[half];          // [3mg][12a][12k] = 432
    c32* Gs = u1[half] + 432;    // [5mai][3mg][12k] = 180
    for (int c = r; c < 144; c += 128){
        int a = c/12, k = c - a*12;
        float hv[12];
        #pragma unroll
        for (int g = 0; g < 12; ++g) hv[g] = hh[(g*12+a)*13+k];
        float s0 = 0.f;
        #pragma unroll
        for (int g = 0; g < 12; ++g) s0 += hv[g];
        Gg[a*12+k] = make_float2(s0, 0.f);
        #pragma unroll
        for (int mg = 1; mg < 3; ++mg){
            float ax = 0.f, ay = 0.f;
            #pragma unroll
            for (int g = 0; g < 12; ++g){
                const int tt = M12(mg*g);
                ax += hv[g]*CW12[tt]; ay -= hv[g]*SW12[tt];
            }
            Gg[(mg*12+a)*12+k] = make_float2(ax, ay);
        }
    }
    __syncthreads();

    // F: Gs[mai][mg][k] = sum_a Gg e^{-2pi i ma a/12}; a-parity + +-ma conjugate pairing
    if (r < 108){
        int j = r/36, rr = r - j*36, mg = rr/12, k = rr - mg*12;
        const c32* gp = Gg + mg*144 + k;
        if (j == 0){             // ma = 0
            float sx = 0.f, sy = 0.f;
            #pragma unroll
            for (int a = 0; a < 6; ++a){
                c32 xa = gp[a*12], ya = gp[(a+6)*12];
                sx += xa.x + ya.x; sy += xa.y + ya.y;
            }
            Gs[(2*3+mg)*12+k] = make_float2(sx, sy);
        } else if (j == 1){      // ma = +-1 (odd)
            float Cx=0.f,Cy=0.f,Sx=0.f,Sy=0.f;
            #pragma unroll
            for (int a = 0; a < 6; ++a){
                c32 xa = gp[a*12], ya = gp[(a+6)*12];
                float ux = xa.x - ya.x, uy = xa.y - ya.y;
                const float cc = CW12[a], ss = SW12[a];
                Cx += ux*cc; Cy += uy*cc;
                Sx += ux*ss; Sy += uy*ss;
            }
            Gs[(3*3+mg)*12+k] = make_float2(Cx + Sy, Cy - Sx);  // ma=+1
            Gs[(1*3+mg)*12+k] = make_float2(Cx - Sy, Cy + Sx);  // ma=-1
        } else {                 // ma = +-2 (even)
            float Cx=0.f,Cy=0.f,Sx=0.f,Sy=0.f;
            #pragma unroll
            for (int a = 0; a < 6; ++a){
                c32 xa = gp[a*12], ya = gp[(a+6)*12];
                float ux = xa.x + ya.x, uy = xa.y + ya.y;
                const float cc = CW12[M12(2*a)], ss = SW12[M12(2*a)];
                Cx += ux*cc; Cy += uy*cc;
                Sx += ux*ss; Sy += uy*ss;
            }
            Gs[(4*3+mg)*12+k] = make_float2(Cx + Sy, Cy - Sx);  // ma=+2
            Gs[(0*3+mg)*12+k] = make_float2(Cx - Sy, Cy + Sx);  // ma=-2
        }
    }
    __syncthreads();

    // G: xs2p slot(lm,qt): sum_k dG * G(k,m,q)
    if (r < 30){
        int lm = r/5, qt = r - lm*5;
        int l = lm==0?0:(lm<3?1:2);
        int m = lm==0?0:(lm<3?lm-1:lm-3);
        c32 acc = make_float2(0.f,0.f);
        if (qt < 2*l+1){
            int q = qt - l;
            #pragma unroll
            for (int k = 0; k < 12; ++k){
                float d = fb[O_DG + r*12 + k];
                c32 gvv;
                if (q >= 0) gvv = Gs[((m+2)*3 + q)*12 + k];
                else { c32 w = Gs[((2-m)*3 + (-q))*12 + k]; gvv = make_float2(w.x, -w.y); }
                acc.x += d*gvv.x; acc.y += d*gvv.y;
            }
        }
        xs2p[(n*8+o)*30 + r] = acc;
    }
}

// ---------------- layer 2 + integrate: block per 4 n, all 16 o ----------------
__global__ __launch_bounds__(256) void k_layer2(const c32* __restrict__ cb, const float* __restrict__ fb,
                                                const float* __restrict__ b2, float* __restrict__ feat){
    __shared__ c32 xs2sh[960];    // [4nl][8i][6lm][5qt]
    __shared__ c32 zp2[4][384];   // [nl][16o][24cellpad]
    __shared__ c32 T2[1728];      // [16o][6k][3m][6g], reused per nl
    __shared__ float part[576];   // [16o][36(k,g)]
    int tid = threadIdx.x, n0 = blockIdx.x*4;
    for (int c = tid; c < 960; c += 256) xs2sh[c] = cb[O_XS2P + n0*240 + c];
    __syncthreads();

    for (int c = tid; c < 1408; c += 256){
        int nl = c/352, cc = c - nl*352, o = cc/22, cell = cc - o*22;
        int l, lm;
        if (cell == 0){ l=0; lm=0; }
        else if (cell < 7){ l=1; lm=1+(cell-1)/3; }
        else { l=2; lm=3+(cell-7)/5; }
        const c32* cy = cb + O_CY2P + (o*22+cell)*40;
        const c32* xv0 = xs2sh + nl*240;
        c32 acc = make_float2(0.f,0.f);
        #pragma unroll
        for (int i = 0; i < 8; ++i){
            #pragma unroll
            for (int qt = 0; qt < 5; ++qt){
                c32 xv = xv0[(i*6+lm)*5 + qt];
                c32 yv = cy[i*5+qt];
                acc.x += xv.x*yv.x - xv.y*yv.y;
                acc.y += xv.x*yv.y + xv.y*yv.x;
            }
        }
        float f = (float)(2*l+1);
        zp2[nl][o*24+cell] = make_float2(f*acc.x, f*acc.y);
    }
    __syncthreads();

    for (int nl = 0; nl < 4; ++nl){
        for (int c = tid; c < 288; c += 256){
            int o = c/18, r = c - o*18, k = r/3, m = r - k*3;
            c32 s2v[5];
            #pragma unroll
            for (int pi = 0; pi < 5; ++pi){
                const int p = pi-2; const int ap = p<0?-p:p;
                c32 acc = make_float2(0.f,0.f);
                #pragma unroll
                for (int l = 0; l < 3; ++l){
                    if (l >= ap){
                        float d = fb[O_D2P + ((m*5+pi)*6+k)*4 + l];
                        int cell = (l==0) ? 0 : ((l==1) ? 1+m*3+(p+1) : 7+m*5+(p+2));
                        c32 z = zp2[nl][o*24+cell];
                        acc.x += d*z.x; acc.y += d*z.y;
                    }
                }
                s2v[pi] = acc;
            }
            #pragma unroll
            for (int g = 0; g < 6; ++g){
                c32 t = make_float2(0.f,0.f);
                #pragma unroll
                for (int pi = 0; pi < 5; ++pi){
                    const int tt = M6((pi-2)*g);
                    cmadd(t, s2v[pi], CW6[tt], SW6[tt]);
                }
                T2[((o*6+k)*3+m)*6+g] = t;
            }
        }
        __syncthreads();
        for (int c = tid; c < 576; c += 256){
            int o = c/36, r = c - o*36, k = r/6, g = r - k*6;
            c32 t0 = T2[((o*6+k)*3+0)*6+g];
            c32 t1 = T2[((o*6+k)*3+1)*6+g];
            c32 t2 = T2[((o*6+k)*3+2)*6+g];
            float base = t0.x + b2[o];
            float s = 0.f;
            #pragma unroll
            for (int a = 0; a < 6; ++a){
                float h = base + 2.f*(t1.x*CW6[M6(a)]   - t1.y*SW6[M6(a)])
                               + 2.f*(t2.x*CW6[M6(2*a)] - t2.y*SW6[M6(2*a)]);
                s += h > 0.f ? h : 0.f;
            }
            part[c] = s * fb[O_WINT + k];
        }
        __syncthreads();
        if (tid < 16){
            float s = 0.f;
            #pragma unroll
            for (int j = 0; j < 36; ++j) s += part[tid*36+j];
            feat[(n0+nl)*16+tid] = s * (1.f/36.f);
        }
        __syncthreads();
    }
}

// ---------------- max-pool over 512 points per (b,o) ----------------
__global__ __launch_bounds__(64) void k_pool(const float* __restrict__ feat, float* __restrict__ pool){
    int b = blockIdx.x >> 4, o = blockIdx.x & 15;
    int tid = threadIdx.x;
    float m = -3.4e38f;
    for (int pt = tid; pt < 512; pt += 64)
        m = fmaxf(m, feat[(b*512+pt)*16 + o]);
    for (int off = 32; off; off >>= 1) m = fmaxf(m, __shfl_down(m, off));
    if (tid == 0) pool[b*16 + o] = m;
}

// ---------------- head ----------------
__global__ __launch_bounds__(64) void k_head(const float* __restrict__ pool, const float* __restrict__ w_out,
                                             const float* __restrict__ bias_out, float* __restrict__ out){
    int tid = threadIdx.x;
    if (tid < 40){
        int b = tid/10, j = tid%10;
        float s = bias_out[j];
        for (int o = 0; o < 16; ++o) s += pool[b*16+o]*w_out[j*16+o];
        out[tid] = s;
    }
}

extern "C" void kernel_launch(void* const* d_in, const int* in_sizes, int n_in,
                              void* d_out, int out_size, void* d_ws, size_t ws_size,
                              hipStream_t stream){
    const float* x        = (const float*)d_in[0];
    const float* w1       = (const float*)d_in[1];
    const float* b1       = (const float*)d_in[2];
    const float* w2       = (const float*)d_in[3];
    const float* b2       = (const float*)d_in[4];
    const float* w_out    = (const float*)d_in[5];
    const float* bias_out = (const float*)d_in[6];
    float* out = (float*)d_out;

    c32*   cb = (c32*)d_ws;
    float* fb = (float*)(cb + N_C32_TOTAL);
    float* feat = fb + O_FEAT;
    float* pool = fb + O_POOL;

    k_setup_pre<<<2, 256, 0, stream>>>(fb);
    k_setup_main<<<163, 256, 0, stream>>>(cb, fb, w1, w2);
    k_s2fft<<<512, 256, 0, stream>>>(x, fb, cb + O_XS);
    k_layer1<<<2048*4, 256, 0, stream>>>(cb, fb, b1, cb + O_XS2P);
    k_layer2<<<512, 256, 0, stream>>>(cb, fb, b2, feat);
    k_pool<<<64, 64, 0, stream>>>(feat, pool);
    k_head<<<1, 64, 0, stream>>>(pool, w_out, bias_out, out);
}

// Round 7
// 172.297 us; speedup vs baseline: 1.1535x; 1.0456x over previous
//
#include <hip/hip_runtime.h>
#include <cmath>

typedef float2 c32;

__device__ __forceinline__ void cmadd(c32& acc, c32 a, float cr, float ci){
    acc.x += a.x*cr - a.y*ci;
    acc.y += a.x*ci + a.y*cr;
}

__host__ __device__ constexpr int M12(int x){ return ((x%12)+12)%12; }
__host__ __device__ constexpr int M6(int x){ return ((x%6)+6)%6; }

#define SQ32 0.86602540378443864676f
#define RT22 0.70710678118654752440f
static constexpr float CW12[12] = {1.f, SQ32, 0.5f, 0.f, -0.5f, -SQ32, -1.f, -SQ32, -0.5f, 0.f, 0.5f, SQ32};
static constexpr float SW12[12] = {0.f, 0.5f, SQ32, 1.f, SQ32, 0.5f, 0.f, -0.5f, -SQ32, -1.f, -SQ32, -0.5f};
static constexpr float CW6[6] = {1.f, 0.5f, -0.5f, -1.f, -0.5f, 0.5f};
static constexpr float SW6[6] = {0.f, SQ32, SQ32, 0.f, -SQ32, -SQ32};
static constexpr float CW8[8] = {1.f, RT22, 0.f, -RT22, -1.f, -RT22, 0.f, RT22};
static constexpr float SW8[8] = {0.f, RT22, 1.f, RT22, 0.f, -RT22, -1.f, -RT22};
static constexpr float CW20_[6] = {1.f, 0.95105651629515357212f, 0.80901699437494742410f,
                                   0.58778525229247312917f, 0.30901699437494742410f, 0.f};
static constexpr float SW20_[6] = {0.f, 0.30901699437494742410f, 0.58778525229247312917f,
                                   0.80901699437494742410f, 0.95105651629515357212f, 1.f};

// ---------------- workspace layout ----------------
// float2 region
#define O_CY1  0                   // [8o][66]
#define O_CY2P 528                 // [16o][22cell][8i][5qt]
#define O_XS   (O_CY2P + 14080)    // [2048n][36]
#define O_XS2P (O_XS + 73728)      // [2048n][8i][30slot]
#define N_C32_TOTAL (O_XS2P + 2048*8*30)

// float region
#define O_S2D  0                   // [6l][20k][11mi]
#define O_D1S  1752                // [66cell][8l][12k] sorted-by-lmin cells
#define O_DG   (O_D1S + 6336)      // [30slot][12k]
#define O_D2P  (O_DG + 360)        // [15(m,pi)][6k][4lp]
#define O_FEAT (O_D2P + 360)       // [2048n][16o]
#define O_POOL (O_FEAT + 32768)    // [64]

#define DPI 3.14159265358979323846

// sorted cell enumeration: cells grouped by L = max(m,|p|), m>=0
__device__ __forceinline__ void cell_decode(int c, int& L, int& m, int& p){
    int base;
    if (c < 1){ L=0; base=0; } else if (c < 6){ L=1; base=1; }
    else if (c < 15){ L=2; base=6; } else if (c < 28){ L=3; base=15; }
    else if (c < 45){ L=4; base=28; } else { L=5; base=45; }
    int r = c - base;
    if (r < 2*L){ m = r>>1; p = (r&1)? L : -L; }
    else { m = L; p = (r - 2*L) - L; }
}

// ---------------- Wigner-d via factorial table ----------------
static constexpr double FCT[13] = {1.,1.,2.,6.,24.,120.,720.,5040.,40320.,
                                   362880.,3628800.,39916800.,479001600.};

__device__ __forceinline__ double dipow(double b, int e){
    double r = 1.0;
    while (e){ if (e & 1) r *= b; b *= b; e >>= 1; }
    return r;
}

__device__ double dev_wig(int l, int mp, int m, double beta){
    int k0 = max(0, m - mp), k1 = min(l + m, l - mp);
    double c = cos(0.5*beta), s = sin(0.5*beta);
    double fnum = sqrt(FCT[l+mp]*FCT[l-mp]*FCT[l+m]*FCT[l-m]);
    double acc = 0.0;
    for (int k = k0; k <= k1; ++k){
        double t = fnum / (FCT[l+m-k]*FCT[k]*FCT[mp-m+k]*FCT[l-mp-k])
                 * dipow(c, 2*l-2*k+m-mp) * dipow(s, mp-m+2*k);
        acc += ((mp-m+k) & 1) ? -t : t;
    }
    return acc;
}

__device__ double dev_qw(int b, double beta){
    double s = 0.0;
    for (int j = 0; j < b; ++j) s += sin((2.0*j+1.0)*beta)/(2.0*j+1.0);
    return (2.0/b)*sin(beta)*s;
}

// ---------------- single setup kernel: blocks 0..127 = CY2P per (o,i); 128+ = item pool ----------------
__global__ __launch_bounds__(256) void k_setup(c32* cb, float* fb,
                                               const float* __restrict__ w1,
                                               const float* __restrict__ w2){
    __shared__ float wsh[144];
    __shared__ float s_d2sg[225];
    __shared__ c32 W1s[3][8][5];
    __shared__ c32 Rs[3][5][5];
    int bid = blockIdx.x, tid = threadIdx.x;
    if (bid < 128){
        int o = bid >> 3, i = bid & 7;
        for (int c = tid; c < 144; c += 256) wsh[c] = w2[(i*16+o)*144 + c];
        // D2SG computed locally (no dependency on a prior kernel)
        for (int c = tid; c < 225; c += 256){
            int qi = c%5; int t = c/5; int pi = t%5; t /= 5; int ib = t%3; int l = t/3;
            float v = 0.f;
            if (pi < 2*l+1 && qi < 2*l+1){ double beta = (ib+1)*DPI/24.0; v = (float)dev_wig(l, pi-l, qi-l, beta); }
            s_d2sg[c] = v;
        }
        __syncthreads();
        for (int c = tid; c < 120; c += 256){
            int ib = c/40, r = c%40, ia = r/5, qi = r%5;
            int q = qi - 2; int qm = ((q%6)+6)%6;
            float wr = CW6[qm], wi = SW6[qm];
            float er = 1.f, ei = 0.f, sx = 0.f, sy = 0.f;
            const float* wrow = wsh + ib*48 + ia*6;
            #pragma unroll
            for (int ig = 0; ig < 6; ++ig){
                float w = wrow[ig];
                sx += w*er; sy += w*ei;
                float nr = er*wr - ei*wi; ei = er*wi + ei*wr; er = nr;
            }
            W1s[ib][ia][qi] = make_float2(sx, sy);
        }
        __syncthreads();
        for (int c = tid; c < 75; c += 256){
            int ib = c/25, r = c%25, pi = r/5, qi = r%5;
            int p = pi - 2; int pm = ((p%8)+8)%8;
            float wr = CW8[pm], wi = SW8[pm];
            float er = 1.f, ei = 0.f;
            c32 acc = make_float2(0.f,0.f);
            #pragma unroll
            for (int ia = 0; ia < 8; ++ia){
                c32 wv = W1s[ib][ia][qi];
                acc.x += wv.x*er - wv.y*ei;
                acc.y += wv.x*ei + wv.y*er;
                float nr = er*wr - ei*wi; ei = er*wi + ei*wr; er = nr;
            }
            Rs[ib][pi][qi] = acc;
        }
        __syncthreads();
        for (int c = tid; c < 110; c += 256){
            int cell = c/5, qt = c%5;
            int l, p;
            if (cell == 0){ l=0; p=0; }
            else if (cell < 7){ l=1; p=(cell-1)%3 - 1; }
            else { l=2; p=(cell-7)%5 - 2; }
            c32 acc = make_float2(0.f,0.f);
            if (qt < 2*l+1){
                int q = qt - l;
                #pragma unroll
                for (int ib = 0; ib < 3; ++ib){
                    float d = s_d2sg[(l*3+ib)*25 + (p+l)*5 + (q+l)];
                    c32 rv = Rs[ib][p+2][q+2];
                    acc.x += d*rv.x; acc.y += d*rv.y;
                }
            }
            cb[O_CY2P + ((o*22+cell)*8 + i)*5 + qt] = acc;
        }
        return;
    }
    // item pool: S2D 1320, CY1 528, D1S 6336, DG 360, D2P 360 = 8904
    int gid = (bid-128)*256 + tid;
    if (gid < 1320){   // S2D [6l][20k][11mi]
        int mi = gid%11; int t = gid/11; int k = t%20; int l = t/20;
        float v = 0.f;
        if (mi < 2*l+1){
            double beta = DPI*(2*k+1)/40.0;
            v = (float)(dev_wig(l, mi-l, 0, beta) * dev_qw(10, beta));
        }
        fb[O_S2D+gid] = v; return;
    }
    gid -= 1320;
    if (gid < 528){    // CY1 [8o][6l][11pi], D1SG inline
        int pi = gid%11; int t = gid/11; int l = t%6; int o = t/6;
        c32 acc = make_float2(0.f,0.f);
        if (pi < 2*l+1){
            int p = pi - l;
            int pm = ((p%8)+8)%8;
            float wr = CW8[pm], wi = SW8[pm];
            for (int ib = 0; ib < 3; ++ib){
                float d = (float)dev_wig(l, pi-l, 0, (ib+1)*DPI/24.0);
                float er = 1.f, ei = 0.f, sx = 0.f, sy = 0.f;
                #pragma unroll
                for (int ia = 0; ia < 8; ++ia){
                    float w = w1[o*24 + ib*8 + ia];
                    sx += w*er; sy += w*ei;
                    float nr = er*wr - ei*wi; ei = er*wi + ei*wr; er = nr;
                }
                acc.x += d*sx; acc.y += d*sy;
            }
        }
        cb[O_CY1 + (o*6+l)*11 + pi] = acc;
        return;
    }
    gid -= 528;
    if (gid < 6336){   // D1S [66cell][8l][12k]
        int k = gid%12; int t = gid/12; int l = t%8; int cell = t/8;
        int L, m, p; cell_decode(cell, L, m, p);
        float v = 0.f;
        if (l < 6 && l >= L){
            double beta = DPI*(2*k+1)/24.0;
            v = (float)dev_wig(l, m, p, beta);
        }
        fb[O_D1S+gid] = v; return;
    }
    gid -= 6336;
    if (gid < 360){    // DG [30slot][12k]
        int k = gid%12; int slot = gid/12;
        int lm = slot/5, qt = slot%5;
        int l = lm==0?0:(lm<3?1:2);
        int m = lm==0?0:(lm<3?lm-1:lm-3);
        float v = 0.f;
        if (qt < 2*l+1){
            double beta = DPI*(2*k+1)/24.0;
            v = (float)(dev_wig(l, m, qt-l, beta) * dev_qw(6, beta));
        }
        fb[O_DG+gid] = v; return;
    }
    gid -= 360;
    if (gid < 360){    // D2P [15(m,pi)][6k][4lp]
        int lp = gid%4; int t = gid/4; int k = t%6; int cell = t/6;
        int m = cell/5, pi = cell%5, p = pi-2, ap = p<0?-p:p;
        float v = 0.f;
        if (lp < 3 && lp >= m && lp >= ap){
            double beta = DPI*(2*k+1)/12.0;
            v = (float)dev_wig(lp, m, p, beta);
        }
        fb[O_D2P+gid] = v; return;
    }
}

// ---------------- s2 fft: 4 n per block ----------------
__global__ __launch_bounds__(256) void k_s2fft(const float* __restrict__ x, const float* __restrict__ fb,
                                               c32* __restrict__ XS){
    __shared__ float xsh[1600];      // [4nl][400]
    __shared__ c32 F1[4][20][6];
    int n0 = blockIdx.x*4, tid = threadIdx.x;
    for (int i = tid; i < 1600; i += 256) xsh[i] = x[n0*400 + i];
    __syncthreads();
    for (int i = tid; i < 480; i += 256){
        int nl = i/120, r = i - nl*120, k = r/6, m = r - k*6;
        float wr = CW20_[m], wi = -SW20_[m];   // e^{-2pi i m/20}
        float er = 1.f, ei = 0.f, ax = 0.f, ay = 0.f;
        const float* row = xsh + nl*400 + k*20;
        #pragma unroll
        for (int a = 0; a < 20; ++a){
            float v = row[a];
            ax += v*er; ay += v*ei;
            float nr = er*wr - ei*wi; ei = er*wi + ei*wr; er = nr;
        }
        F1[nl][k][m] = make_float2(ax, ay);
    }
    __syncthreads();
    if (tid < 144){
        int nl = tid/36, t = tid - nl*36;
        int l = 0; while ((l+1)*(l+1) <= t) ++l;
        int mi = t - l*l; int m = mi - l;
        c32 acc = make_float2(0.f,0.f);
        for (int k = 0; k < 20; ++k){
            float d = fb[O_S2D + (l*20+k)*11 + mi];
            c32 F = (m >= 0) ? F1[nl][k][m] : make_float2(F1[nl][k][-m].x, -F1[nl][k][-m].y);
            acc.x += d*F.x; acc.y += d*F.y;
        }
        XS[(n0+nl)*36 + t] = acc;
    }
}

// ---------------- layer 1 megakernel: per (n,o), round-5 proven structure ----------------
__global__ __launch_bounds__(256) void k_layer1(const c32* __restrict__ cb, const float* __restrict__ fb,
                                                const float* __restrict__ b1, c32* __restrict__ xs2p){
    __shared__ c32 xs_sh[36];
    __shared__ c32 u1[864];   // zps[6][66] -> T[6m][12g][12k]
    __shared__ c32 u2[936];   // S[66mp][12k] -> h float[12g][12a][13kpad]
    __shared__ c32 Gg[432];   // [3mg][12a][12k]
    __shared__ c32 Gs[180];   // [5mai][3mg][12k]
    int tid = threadIdx.x;
    int n = blockIdx.x >> 3, o = blockIdx.x & 7;
    float bias = b1[o];
    if (tid < 36) xs_sh[tid] = cb[O_XS + n*36 + tid];
    __syncthreads();

    // A: zps[l][mp] = (2l+1) * xs_l(m) * conjY1_l(p), m>=0, zero-padded
    for (int c = tid; c < 396; c += 256){
        int l = c/66, mp = c - l*66, m = mp/11, pi = mp - m*11;
        int p = pi - 5, ap = p < 0 ? -p : p;
        c32 v = make_float2(0.f, 0.f);
        if (m <= l && ap <= l){
            c32 a = xs_sh[l*l + l + m];
            c32 b = cb[O_CY1 + o*66 + l*11 + p + l];
            float f = (float)(2*l+1);
            v.x = f*(a.x*b.x - a.y*b.y); v.y = f*(a.x*b.y + a.y*b.x);
        }
        u1[c] = v;
    }
    __syncthreads();

    // B: S[mp][k] = sum_{l>=L} d1s * zps ; lane = (sorted cell, k-half)
    if (tid < 132){
        int cell = tid >> 1, kh = tid & 1;
        int L, m, p; cell_decode(cell, L, m, p);
        int mp = m*11 + p + 5;
        c32 acc[6];
        #pragma unroll
        for (int j = 0; j < 6; ++j) acc[j] = make_float2(0.f,0.f);
        for (int l = L; l < 6; ++l){
            c32 z = u1[l*66 + mp];
            const float* dp = fb + O_D1S + (cell*8 + l)*12 + kh*6;
            #pragma unroll
            for (int j = 0; j < 6; ++j){
                float d = dp[j];
                acc[j].x += d*z.x; acc[j].y += d*z.y;
            }
        }
        #pragma unroll
        for (int j = 0; j < 6; ++j) u2[mp*12 + kh*6 + j] = acc[j];
    }
    __syncthreads();

    // C: T[m][g][k] = sum_p S w12^{pg}; +-p Hermitian pairing AND g<->g+6 parity
    if (tid < 72){
        int m = tid/12, k = tid - m*12;
        c32 S0 = u2[(m*11+5)*12 + k];
        c32 E[5], O[5];
        #pragma unroll
        for (int p = 1; p <= 5; ++p){
            c32 a = u2[(m*11+5+p)*12 + k], b = u2[(m*11+5-p)*12 + k];
            E[p-1] = make_float2(a.x+b.x, a.y+b.y);
            O[p-1] = make_float2(a.x-b.x, a.y-b.y);
        }
        #pragma unroll
        for (int g = 0; g < 6; ++g){
            float vex=0.f, vey=0.f, vox=0.f, voy=0.f;
            #pragma unroll
            for (int p = 1; p <= 5; ++p){
                const float cc = CW12[M12(p*g)], ss = SW12[M12(p*g)];
                float vx = E[p-1].x*cc - O[p-1].y*ss;
                float vy = E[p-1].y*cc + O[p-1].x*ss;
                if (p & 1){ vox += vx; voy += vy; } else { vex += vx; vey += vy; }
            }
            float tex = S0.x + vex, tey = S0.y + vey;
            u1[(m*12+g)*12 + k]   = make_float2(tex + vox, tey + voy);
            u1[(m*12+g+6)*12 + k] = make_float2(tex - vox, tey - voy);
        }
    }
    __syncthreads();

    // D: h[g][a][k] = ReLU( T0 + 2*sum_{m>0} Re(Tm w12^{ma}) + bias ), a-parity shared
    float* hh = (float*)u2;   // [12g][12a][13k]
    if (tid < 144){
        int g = tid/12, k = tid - g*12;
        c32 t1 = u1[(1*12+g)*12+k], t2 = u1[(2*12+g)*12+k], t3 = u1[(3*12+g)*12+k];
        c32 t4 = u1[(4*12+g)*12+k], t5 = u1[(5*12+g)*12+k];
        float base = u1[(0*12+g)*12+k].x + bias;
        #pragma unroll
        for (int a = 0; a < 6; ++a){
            float od = t1.x*CW12[M12(1*a)] - t1.y*SW12[M12(1*a)]
                     + t3.x*CW12[M12(3*a)] - t3.y*SW12[M12(3*a)]
                     + t5.x*CW12[M12(5*a)] - t5.y*SW12[M12(5*a)];
            float ev = t2.x*CW12[M12(2*a)] - t2.y*SW12[M12(2*a)]
                     + t4.x*CW12[M12(4*a)] - t4.y*SW12[M12(4*a)];
            float h0 = base + 2.f*(ev+od);
            float h1 = base + 2.f*(ev-od);
            hh[(g*12+a)*13+k]     = h0 > 0.f ? h0 : 0.f;
            hh[(g*12+a+6)*13+k]   = h1 > 0.f ? h1 : 0.f;
        }
    }
    __syncthreads();

    // E: Gg[mg][a][k] = sum_g h e^{-2pi i mg g/12}, mg=0 real-sum special case
    if (tid < 144){
        int a = tid/12, k = tid - a*12;
        float hv[12];
        #pragma unroll
        for (int g = 0; g < 12; ++g) hv[g] = hh[(g*12+a)*13+k];
        float s0 = 0.f;
        #pragma unroll
        for (int g = 0; g < 12; ++g) s0 += hv[g];
        Gg[a*12+k] = make_float2(s0, 0.f);
        #pragma unroll
        for (int mg = 1; mg < 3; ++mg){
            float ax = 0.f, ay = 0.f;
            #pragma unroll
            for (int g = 0; g < 12; ++g){
                const int tt = M12(mg*g);
                ax += hv[g]*CW12[tt]; ay -= hv[g]*SW12[tt];
            }
            Gg[(mg*12+a)*12+k] = make_float2(ax, ay);
        }
    }
    __syncthreads();

    // F: Gs[mai][mg][k] = sum_a Gg e^{-2pi i ma a/12}; a-parity + +-ma conjugate pairing
    if (tid < 108){
        int j = tid/36, rr = tid - j*36, mg = rr/12, k = rr - mg*12;
        const c32* gp = Gg + mg*144 + k;
        if (j == 0){             // ma = 0
            float sx = 0.f, sy = 0.f;
            #pragma unroll
            for (int a = 0; a < 6; ++a){
                c32 xa = gp[a*12], ya = gp[(a+6)*12];
                sx += xa.x + ya.x; sy += xa.y + ya.y;
            }
            Gs[(2*3+mg)*12+k] = make_float2(sx, sy);
        } else if (j == 1){      // ma = +-1 (odd)
            float Cx=0.f,Cy=0.f,Sx=0.f,Sy=0.f;
            #pragma unroll
            for (int a = 0; a < 6; ++a){
                c32 xa = gp[a*12], ya = gp[(a+6)*12];
                float ux = xa.x - ya.x, uy = xa.y - ya.y;
                const float cc = CW12[a], ss = SW12[a];
                Cx += ux*cc; Cy += uy*cc;
                Sx += ux*ss; Sy += uy*ss;
            }
            Gs[(3*3+mg)*12+k] = make_float2(Cx + Sy, Cy - Sx);  // ma=+1
            Gs[(1*3+mg)*12+k] = make_float2(Cx - Sy, Cy + Sx);  // ma=-1
        } else {                 // ma = +-2 (even)
            float Cx=0.f,Cy=0.f,Sx=0.f,Sy=0.f;
            #pragma unroll
            for (int a = 0; a < 6; ++a){
                c32 xa = gp[a*12], ya = gp[(a+6)*12];
                float ux = xa.x + ya.x, uy = xa.y + ya.y;
                const float cc = CW12[M12(2*a)], ss = SW12[M12(2*a)];
                Cx += ux*cc; Cy += uy*cc;
                Sx += ux*ss; Sy += uy*ss;
            }
            Gs[(4*3+mg)*12+k] = make_float2(Cx + Sy, Cy - Sx);  // ma=+2
            Gs[(0*3+mg)*12+k] = make_float2(Cx - Sy, Cy + Sx);  // ma=-2
        }
    }
    __syncthreads();

    // G: xs2p slot(lm,qt): sum_k dG * G(k,m,q)
    if (tid < 30){
        int lm = tid/5, qt = tid - lm*5;
        int l = lm==0?0:(lm<3?1:2);
        int m = lm==0?0:(lm<3?lm-1:lm-3);
        c32 acc = make_float2(0.f,0.f);
        if (qt < 2*l+1){
            int q = qt - l;
            #pragma unroll
            for (int k = 0; k < 12; ++k){
                float d = fb[O_DG + tid*12 + k];
                c32 gvv;
                if (q >= 0) gvv = Gs[((m+2)*3 + q)*12 + k];
                else { c32 w = Gs[((2-m)*3 + (-q))*12 + k]; gvv = make_float2(w.x, -w.y); }
                acc.x += d*gvv.x; acc.y += d*gvv.y;
            }
        }
        xs2p[(n*8+o)*30 + tid] = acc;
    }
}

// ---------------- layer 2 + integrate: block per 4 n, all 16 o; cy reused across nl ----------------
__global__ __launch_bounds__(256) void k_layer2(const c32* __restrict__ cb, const float* __restrict__ fb,
                                                const float* __restrict__ b2, float* __restrict__ feat){
    __shared__ c32 xs2sh[960];    // [4nl][8i][6lm][5qt]
    __shared__ c32 zp2[4][384];   // [nl][16o][24cellpad]
    __shared__ c32 T2[1728];      // [16o][6k][3m][6g], reused per nl
    __shared__ float part[576];   // [16o][36(k,g)]
    __shared__ float wint_sh[6];
    int tid = threadIdx.x, n0 = blockIdx.x*4;
    for (int c = tid; c < 960; c += 256) xs2sh[c] = cb[O_XS2P + n0*240 + c];
    if (tid < 6){ double beta = DPI*(2*tid+1)/12.0; wint_sh[tid] = (float)dev_qw(3, beta); }
    __syncthreads();

    // Z: cy row loaded once, all 4 nl accumulated in registers
    for (int c = tid; c < 352; c += 256){
        int o = c/22, cell = c - o*22;
        int l, lm;
        if (cell == 0){ l=0; lm=0; }
        else if (cell < 7){ l=1; lm=1+(cell-1)/3; }
        else { l=2; lm=3+(cell-7)/5; }
        const c32* cy = cb + O_CY2P + (o*22+cell)*40;
        c32 acc[4];
        #pragma unroll
        for (int nl = 0; nl < 4; ++nl) acc[nl] = make_float2(0.f,0.f);
        #pragma unroll
        for (int i = 0; i < 8; ++i){
            #pragma unroll
            for (int qt = 0; qt < 5; ++qt){
                c32 yv = cy[i*5+qt];
                #pragma unroll
                for (int nl = 0; nl < 4; ++nl){
                    c32 xv = xs2sh[nl*240 + (i*6+lm)*5 + qt];
                    acc[nl].x += xv.x*yv.x - xv.y*yv.y;
                    acc[nl].y += xv.x*yv.y + xv.y*yv.x;
                }
            }
        }
        float f = (float)(2*l+1);
        #pragma unroll
        for (int nl = 0; nl < 4; ++nl)
            zp2[nl][o*24+cell] = make_float2(f*acc[nl].x, f*acc[nl].y);
    }
    __syncthreads();

    for (int nl = 0; nl < 4; ++nl){
        for (int c = tid; c < 288; c += 256){
            int o = c/18, r = c - o*18, k = r/3, m = r - k*3;
            c32 s2v[5];
            #pragma unroll
            for (int pi = 0; pi < 5; ++pi){
                const int p = pi-2; const int ap = p<0?-p:p;
                c32 acc = make_float2(0.f,0.f);
                #pragma unroll
                for (int l = 0; l < 3; ++l){
                    if (l >= ap){
                        float d = fb[O_D2P + ((m*5+pi)*6+k)*4 + l];
                        int cell = (l==0) ? 0 : ((l==1) ? 1+m*3+(p+1) : 7+m*5+(p+2));
                        c32 z = zp2[nl][o*24+cell];
                        acc.x += d*z.x; acc.y += d*z.y;
                    }
                }
                s2v[pi] = acc;
            }
            #pragma unroll
            for (int g = 0; g < 6; ++g){
                c32 t = make_float2(0.f,0.f);
                #pragma unroll
                for (int pi = 0; pi < 5; ++pi){
                    const int tt = M6((pi-2)*g);
                    cmadd(t, s2v[pi], CW6[tt], SW6[tt]);
                }
                T2[((o*6+k)*3+m)*6+g] = t;
            }
        }
        __syncthreads();
        for (int c = tid; c < 576; c += 256){
            int o = c/36, r = c - o*36, k = r/6, g = r - k*6;
            c32 t0 = T2[((o*6+k)*3+0)*6+g];
            c32 t1 = T2[((o*6+k)*3+1)*6+g];
            c32 t2 = T2[((o*6+k)*3+2)*6+g];
            float base = t0.x + b2[o];
            float s = 0.f;
            #pragma unroll
            for (int a = 0; a < 6; ++a){
                float h = base + 2.f*(t1.x*CW6[M6(a)]   - t1.y*SW6[M6(a)])
                               + 2.f*(t2.x*CW6[M6(2*a)] - t2.y*SW6[M6(2*a)]);
                s += h > 0.f ? h : 0.f;
            }
            part[c] = s * wint_sh[k];
        }
        __syncthreads();
        if (tid < 16){
            float s = 0.f;
            #pragma unroll
            for (int j = 0; j < 36; ++j) s += part[tid*36+j];
            feat[(n0+nl)*16+tid] = s * (1.f/36.f);
        }
        __syncthreads();
    }
}

// ---------------- max-pool over 512 points per (b,o) ----------------
__global__ __launch_bounds__(64) void k_pool(const float* __restrict__ feat, float* __restrict__ pool){
    int b = blockIdx.x >> 4, o = blockIdx.x & 15;
    int tid = threadIdx.x;
    float m = -3.4e38f;
    for (int pt = tid; pt < 512; pt += 64)
        m = fmaxf(m, feat[(b*512+pt)*16 + o]);
    for (int off = 32; off; off >>= 1) m = fmaxf(m, __shfl_down(m, off));
    if (tid == 0) pool[b*16 + o] = m;
}

// ---------------- head ----------------
__global__ __launch_bounds__(64) void k_head(const float* __restrict__ pool, const float* __restrict__ w_out,
                                             const float* __restrict__ bias_out, float* __restrict__ out){
    int tid = threadIdx.x;
    if (tid < 40){
        int b = tid/10, j = tid%10;
        float s = bias_out[j];
        for (int o = 0; o < 16; ++o) s += pool[b*16+o]*w_out[j*16+o];
        out[tid] = s;
    }
}

extern "C" void kernel_launch(void* const* d_in, const int* in_sizes, int n_in,
                              void* d_out, int out_size, void* d_ws, size_t ws_size,
                              hipStream_t stream){
    const float* x        = (const float*)d_in[0];
    const float* w1       = (const float*)d_in[1];
    const float* b1       = (const float*)d_in[2];
    const float* w2       = (const float*)d_in[3];
    const float* b2       = (const float*)d_in[4];
    const float* w_out    = (const float*)d_in[5];
    const float* bias_out = (const float*)d_in[6];
    float* out = (float*)d_out;

    c32*   cb = (c32*)d_ws;
    float* fb = (float*)(cb + N_C32_TOTAL);
    float* feat = fb + O_FEAT;
    float* pool = fb + O_POOL;

    k_setup<<<163, 256, 0, stream>>>(cb, fb, w1, w2);
    k_s2fft<<<512, 256, 0, stream>>>(x, fb, cb + O_XS);
    k_layer1<<<2048*8, 256, 0, stream>>>(cb, fb, b1, cb + O_XS2P);
    k_layer2<<<512, 256, 0, stream>>>(cb, fb, b2, feat);
    k_pool<<<64, 64, 0, stream>>>(feat, pool);
    k_head<<<1, 64, 0, stream>>>(pool, w_out, bias_out, out);
}